// Round 3
// baseline (203.728 us; speedup 1.0000x reference)
//
#include <hip/hip_runtime.h>

// HMULayer omega: out[b][n] = exp(-(lam_n*||x_b-mu_n||^2 + sum_k om_nk*((x_b-mu_n).v_nk)^2)/D)
// B=1024, N=8192, D=256, K=8. 9 fused bf16 MFMA GEMMs sharing A=x.
// R3: Config B — BT=256, 4 b-subtiles/wave (36 MFMA vs 13 ds_read_b128 per kt),
//     p2 rewritten as 1 block/n with float4 loads + parallel waves.

#define B_SZ 1024
#define N_SZ 8192
#define D_SZ 256
#define K_SZ 8

#define BT 256          // b-tile per block (4 subtiles of 16 per wave)
#define NT 16           // n-tile per block
#define LDS_STRIDE 40   // 32 bf16 + 8 pad -> 80B row stride

typedef __bf16 bf16x8 __attribute__((ext_vector_type(8)));
typedef float f32x4 __attribute__((ext_vector_type(4)));
typedef unsigned short u16x8 __attribute__((ext_vector_type(8)));

__device__ __forceinline__ float wave_reduce(float s) {
#pragma unroll
  for (int off = 32; off > 0; off >>= 1) s += __shfl_down(s, off);
  return s;
}

// P1: x2[b] = sum_d x[b][d]^2. One wave per b, one float4 per lane. grid=256, block=256.
__global__ void p1_x2(const float* __restrict__ x, float* __restrict__ x2) {
  const int w = threadIdx.x >> 6, lane = threadIdx.x & 63;
  const int b = blockIdx.x * 4 + w;
  float4 t = *(const float4*)(x + (size_t)b * D_SZ + 4 * lane);
  float s = t.x * t.x + t.y * t.y + t.z * t.z + t.w * t.w;
  s = wave_reduce(s);
  if (lane == 0) x2[b] = s;
}

// P2: mu2[n], muv[n][k]. One block per n; wave w does k=2w,2w+1; wave 0 also mu2.
__global__ void p2_mu(const float* __restrict__ mu, const float* __restrict__ v,
                      float* __restrict__ mu2, float* __restrict__ muv) {
  __shared__ __align__(16) float mulds[D_SZ];
  const int n = blockIdx.x;
  const int w = threadIdx.x >> 6, lane = threadIdx.x & 63;
  if (w == 0) {
    float4 m4 = *(const float4*)(mu + (size_t)n * D_SZ + 4 * lane);
    *(float4*)(mulds + 4 * lane) = m4;
    float s = m4.x * m4.x + m4.y * m4.y + m4.z * m4.z + m4.w * m4.w;
    s = wave_reduce(s);
    if (lane == 0) mu2[n] = s;
  }
  __syncthreads();
  float4 m4 = *(const float4*)(mulds + 4 * lane);
#pragma unroll
  for (int kk = 0; kk < 2; ++kk) {
    const int k = w * 2 + kk;
    float4 v4 = *(const float4*)(v + ((size_t)n * K_SZ + k) * D_SZ + 4 * lane);
    float s = m4.x * v4.x + m4.y * v4.y + m4.z * v4.z + m4.w * v4.w;
    s = wave_reduce(s);
    if (lane == 0) muv[n * K_SZ + k] = s;
  }
}

__device__ __forceinline__ void cvt16_store(const float* __restrict__ src,
                                            unsigned short* dst /* 16B aligned */) {
  const float4* p4 = (const float4*)src;
  float fv[16];
#pragma unroll
  for (int e = 0; e < 4; ++e) {
    float4 t = p4[e];
    fv[4 * e + 0] = t.x; fv[4 * e + 1] = t.y;
    fv[4 * e + 2] = t.z; fv[4 * e + 3] = t.w;
  }
  u16x8 lo, hi;
#pragma unroll
  for (int e = 0; e < 8; ++e) {
    lo[e] = __builtin_bit_cast(unsigned short, (__bf16)fv[e]);
    hi[e] = __builtin_bit_cast(unsigned short, (__bf16)fv[e + 8]);
  }
  *(u16x8*)dst = lo;
  *(u16x8*)(dst + 8) = hi;
}

__global__ __launch_bounds__(256, 2)
void hmu_main(const float* __restrict__ x, const float* __restrict__ mu,
              const float* __restrict__ lam, const float* __restrict__ v,
              const float* __restrict__ om, const float* __restrict__ ws,
              float* __restrict__ out) {
  __shared__ __align__(16) unsigned short As[BT * LDS_STRIDE];      // [b:256][k:32(+8)]
  __shared__ __align__(16) unsigned short Bs[NT * 9 * LDS_STRIDE];  // [n*9+j:144][k:32(+8)]

  const float* ws_x2 = ws;
  const float* ws_mu2 = ws + B_SZ;
  const float* ws_muv = ws + B_SZ + N_SZ;

  const int tid = threadIdx.x;
  const int lane = tid & 63;
  const int w = tid >> 6;       // wave 0..3, owns b-subtiles {4w .. 4w+3}
  const int m = lane & 15;      // MFMA row (A) / col (B,n) / col (C)
  const int kg = lane >> 4;     // k-group

  const int n0 = blockIdx.x * NT;
  const int b0 = blockIdx.y * BT;

  f32x4 acc[4][9];
#pragma unroll
  for (int bs = 0; bs < 4; ++bs)
#pragma unroll
    for (int j = 0; j < 9; ++j) acc[bs][j] = (f32x4){0.f, 0.f, 0.f, 0.f};

  for (int kt = 0; kt < 8; ++kt) {
    const int k0 = kt * 32;
    // --- stage A: 256 rows x 32 bf16; (row,half) over 512, 2 per thread ---
#pragma unroll
    for (int it = 0; it < 2; ++it) {
      int idx = tid + 256 * it;
      int row = idx >> 1, half = idx & 1;
      cvt16_store(x + (size_t)(b0 + row) * D_SZ + k0 + half * 16,
                  &As[row * LDS_STRIDE + half * 16]);
    }
    // --- stage B: 144 rows (row = n*9 + j; j=0 -> mu, j>=1 -> v[j-1]) ---
#pragma unroll
    for (int it = 0; it < 2; ++it) {
      int idx = tid + 256 * it;
      if (idx < 288) {
        int row = idx >> 1, half = idx & 1;
        int nl = row / 9;
        int j = row - nl * 9;
        const float* src = (j == 0)
            ? mu + (size_t)(n0 + nl) * D_SZ + k0 + half * 16
            : v + (size_t)((n0 + nl) * K_SZ + (j - 1)) * D_SZ + k0 + half * 16;
        cvt16_store(src, &Bs[row * LDS_STRIDE + half * 16]);
      }
    }
    __syncthreads();

    bf16x8 af[4];
#pragma unroll
    for (int bs = 0; bs < 4; ++bs) {
      int r = (4 * w + bs) * 16 + m;
      af[bs] = *(const bf16x8*)&As[r * LDS_STRIDE + kg * 8];
    }
#pragma unroll
    for (int j = 0; j < 9; ++j) {
      bf16x8 bfr = *(const bf16x8*)&Bs[(m * 9 + j) * LDS_STRIDE + kg * 8];
#pragma unroll
      for (int bs = 0; bs < 4; ++bs)
        acc[bs][j] = __builtin_amdgcn_mfma_f32_16x16x32_bf16(af[bs], bfr, acc[bs][j], 0, 0, 0);
    }
    __syncthreads();
  }

  // --- epilogue: per-lane, C/D layout col=lane&15 (n), row=kg*4+reg (b) ---
  const int n = n0 + m;
  const float lam_n = lam[n];
  const float mu2_n = ws_mu2[n];
  float omr[8], muvr[8];
#pragma unroll
  for (int k = 0; k < 8; ++k) {
    omr[k] = om[n * 8 + k];
    muvr[k] = ws_muv[n * 8 + k];
  }
#pragma unroll
  for (int bs = 0; bs < 4; ++bs) {
#pragma unroll
    for (int r = 0; r < 4; ++r) {
      int b = b0 + (4 * w + bs) * 16 + kg * 4 + r;
      float x2b = ws_x2[b];
      float c0 = acc[bs][0][r];
      float q = lam_n * (x2b - 2.f * c0 + mu2_n);
#pragma unroll
      for (int k = 0; k < 8; ++k) {
        float p = acc[bs][k + 1][r] - muvr[k];
        q = fmaf(omr[k] * p, p, q);
      }
      out[(size_t)b * N_SZ + n] = __expf(q * (-1.0f / 256.0f));
    }
  }
}

extern "C" void kernel_launch(void* const* d_in, const int* in_sizes, int n_in,
                              void* d_out, int out_size, void* d_ws, size_t ws_size,
                              hipStream_t stream) {
  const float* x   = (const float*)d_in[0];
  const float* mu  = (const float*)d_in[1];
  const float* lam = (const float*)d_in[2];
  const float* v   = (const float*)d_in[3];
  const float* om  = (const float*)d_in[4];
  float* out = (float*)d_out;
  float* ws  = (float*)d_ws;   // [x2:1024][mu2:8192][muv:65536] fp32 = 292KB

  p1_x2<<<B_SZ / 4, 256, 0, stream>>>(x, ws);
  p2_mu<<<N_SZ, 256, 0, stream>>>(mu, v, ws + B_SZ, ws + B_SZ + N_SZ);
  dim3 grid(N_SZ / NT, B_SZ / BT);
  hmu_main<<<grid, 256, 0, stream>>>(x, mu, lam, v, om, ws, out);
}

// Round 4
// 172.059 us; speedup vs baseline: 1.1841x; 1.1841x over previous
//
#include <hip/hip_runtime.h>

// HMULayer omega: out[b][n] = exp(-(lam_n*||x_b-mu_n||^2 + sum_k om_nk*((x_b-mu_n).v_nk)^2)/D)
// B=1024, N=8192, D=256, K=8. 9 fused bf16 MFMA GEMMs sharing A=x.
// R4: bf16 prepack (x -> px, [mu;v] -> pw) + global_load_lds width-16 staging
//     (m97 ladder step). BT=128 (4096 blocks — R3 showed BT=256 kills occupancy).
//     Fallback to R2-style in-loop cvt staging if ws_size too small.

#define B_SZ 1024
#define N_SZ 8192
#define D_SZ 256
#define K_SZ 8

#define BT 128
#define NT 16

typedef __bf16 bf16x8 __attribute__((ext_vector_type(8)));
typedef float f32x4 __attribute__((ext_vector_type(4)));
typedef unsigned short u16x4 __attribute__((ext_vector_type(4)));
typedef unsigned short u16x8 __attribute__((ext_vector_type(8)));

// ws byte offsets
#define WS_X2   0u          // f32[1024]
#define WS_MU2  4096u       // f32[8192]
#define WS_MUV  36864u      // f32[65536]
#define WS_PX   299008u     // bf16[1024*256]   (512 KB)
#define WS_PW   823296u     // bf16[8192*9*256] (36 MB)
#define WS_NEED (823296ull + 37748736ull)

__device__ __forceinline__ float wave_reduce(float s) {
#pragma unroll
  for (int off = 32; off > 0; off >>= 1) s += __shfl_down(s, off);
  return s;
}

__device__ __forceinline__ u16x4 cvt4(float4 t) {
  u16x4 r;
  r[0] = __builtin_bit_cast(unsigned short, (__bf16)t.x);
  r[1] = __builtin_bit_cast(unsigned short, (__bf16)t.y);
  r[2] = __builtin_bit_cast(unsigned short, (__bf16)t.z);
  r[3] = __builtin_bit_cast(unsigned short, (__bf16)t.w);
  return r;
}

__device__ __forceinline__ void glds16(const void* g, const void* l) {
  __builtin_amdgcn_global_load_lds(
      (const __attribute__((address_space(1))) void*)g,
      (__attribute__((address_space(3))) void*)l, 16, 0, 0);
}

// ---- prep_x: x2[b] + px bf16 pack. One wave per b. grid=256, block=256. ----
__global__ void prep_x(const float* __restrict__ x, float* __restrict__ x2,
                       unsigned short* __restrict__ px) {
  const int w = threadIdx.x >> 6, lane = threadIdx.x & 63;
  const int b = blockIdx.x * 4 + w;
  float4 t = *(const float4*)(x + (size_t)b * D_SZ + 4 * lane);
  *(u16x4*)(px + (size_t)b * D_SZ + 4 * lane) = cvt4(t);
  float s = t.x * t.x + t.y * t.y + t.z * t.z + t.w * t.w;
  s = wave_reduce(s);
  if (lane == 0) x2[b] = s;
}

// ---- prep_w: mu2[n], muv[n][k], pw[n][j][k] bf16 (j=0 mu, j>=1 v). 1 block/n. ----
__global__ void prep_w(const float* __restrict__ mu, const float* __restrict__ v,
                       float* __restrict__ mu2, float* __restrict__ muv,
                       unsigned short* __restrict__ pw) {
  __shared__ __align__(16) float mulds[D_SZ];
  const int n = blockIdx.x;
  const int w = threadIdx.x >> 6, lane = threadIdx.x & 63;
  if (w == 0) {
    float4 m4 = *(const float4*)(mu + (size_t)n * D_SZ + 4 * lane);
    *(float4*)(mulds + 4 * lane) = m4;
    *(u16x4*)(pw + (size_t)n * 9 * D_SZ + 4 * lane) = cvt4(m4);
    float s = m4.x * m4.x + m4.y * m4.y + m4.z * m4.z + m4.w * m4.w;
    s = wave_reduce(s);
    if (lane == 0) mu2[n] = s;
  }
  __syncthreads();
  float4 m4 = *(const float4*)(mulds + 4 * lane);
#pragma unroll
  for (int kk = 0; kk < 2; ++kk) {
    const int k = w * 2 + kk;
    float4 v4 = *(const float4*)(v + ((size_t)n * K_SZ + k) * D_SZ + 4 * lane);
    *(u16x4*)(pw + ((size_t)n * 9 + k + 1) * D_SZ + 4 * lane) = cvt4(v4);
    float s = m4.x * v4.x + m4.y * v4.y + m4.z * v4.z + m4.w * v4.w;
    s = wave_reduce(s);
    if (lane == 0) muv[n * K_SZ + k] = s;
  }
}

// ---- main (prepacked): global_load_lds staging, unpadded 64B LDS rows ----
__global__ __launch_bounds__(256, 2)
void hmu_main_p(const unsigned short* __restrict__ px,
                const unsigned short* __restrict__ pw,
                const float* __restrict__ lam, const float* __restrict__ om,
                const float* __restrict__ wsf, float* __restrict__ out) {
  __shared__ __align__(16) unsigned short As[BT * 32];       // [b:128][k:32]  8 KB
  __shared__ __align__(16) unsigned short Bs[NT * 9 * 32];   // [j*16+nl][k:32] 9 KB

  const float* ws_x2 = wsf;                    // WS_X2/4
  const float* ws_mu2 = wsf + 1024;            // WS_MU2/4
  const float* ws_muv = wsf + 9216;            // WS_MUV/4

  const int tid = threadIdx.x;
  const int lane = tid & 63;
  const int w = tid >> 6;
  const int m = lane & 15;
  const int kg = lane >> 4;
  const int nl4 = lane >> 2;    // staging: row-within-16
  const int ch = lane & 3;      // staging: 16B chunk within 64B row

  const int n0 = blockIdx.x * NT;
  const int b0 = blockIdx.y * BT;

  f32x4 acc[2][9];
#pragma unroll
  for (int bs = 0; bs < 2; ++bs)
#pragma unroll
    for (int j = 0; j < 9; ++j) acc[bs][j] = (f32x4){0.f, 0.f, 0.f, 0.f};

  for (int kt = 0; kt < 8; ++kt) {
    const int k0 = kt * 32;
    // A: wave w stages rows w*32..w*32+31 (2 instrs x 1KB, 16 rows each)
#pragma unroll
    for (int t = 0; t < 2; ++t) {
      int r0 = w * 32 + t * 16;
      glds16(px + (size_t)(b0 + r0 + nl4) * D_SZ + k0 + ch * 8, As + r0 * 32);
    }
    // B: instr i stages LDS rows i*16..i*16+15  <- global (n0+nl, j=i)
#pragma unroll
    for (int t = 0; t < 3; ++t) {
      int i = w + 4 * t;                 // wave-uniform guard
      if (i < 9)
        glds16(pw + ((size_t)(n0 + nl4) * 9 + i) * D_SZ + k0 + ch * 8,
               Bs + i * 16 * 32);
    }
    __syncthreads();   // compiler emits s_waitcnt vmcnt(0) before barrier

    bf16x8 af[2];
#pragma unroll
    for (int bs = 0; bs < 2; ++bs)
      af[bs] = *(const bf16x8*)&As[((2 * w + bs) * 16 + m) * 32 + kg * 8];
#pragma unroll
    for (int j = 0; j < 9; ++j) {
      bf16x8 bfr = *(const bf16x8*)&Bs[(j * 16 + m) * 32 + kg * 8];
      acc[0][j] = __builtin_amdgcn_mfma_f32_16x16x32_bf16(af[0], bfr, acc[0][j], 0, 0, 0);
      acc[1][j] = __builtin_amdgcn_mfma_f32_16x16x32_bf16(af[1], bfr, acc[1][j], 0, 0, 0);
    }
    __syncthreads();
  }

  // epilogue: C/D layout col(n)=lane&15, row(b)=kg*4+reg
  const int n = n0 + m;
  const float lam_n = lam[n];
  const float mu2_n = ws_mu2[n];
  float omr[8], muvr[8];
#pragma unroll
  for (int k = 0; k < 8; ++k) {
    omr[k] = om[n * 8 + k];
    muvr[k] = ws_muv[n * 8 + k];
  }
#pragma unroll
  for (int bs = 0; bs < 2; ++bs) {
#pragma unroll
    for (int r = 0; r < 4; ++r) {
      int b = b0 + (2 * w + bs) * 16 + kg * 4 + r;
      float x2b = ws_x2[b];
      float c0 = acc[bs][0][r];
      float q = lam_n * (x2b - 2.f * c0 + mu2_n);
#pragma unroll
      for (int k = 0; k < 8; ++k) {
        float p = acc[bs][k + 1][r] - muvr[k];
        q = fmaf(omr[k] * p, p, q);
      }
      out[(size_t)b * N_SZ + n] = __expf(q * (-1.0f / 256.0f));
    }
  }
}

// ================= fallback path (R2): in-loop cvt staging =================
__device__ __forceinline__ void cvt16_store(const float* __restrict__ src,
                                            unsigned short* dst) {
  const float4* p4 = (const float4*)src;
  float fv[16];
#pragma unroll
  for (int e = 0; e < 4; ++e) {
    float4 t = p4[e];
    fv[4 * e + 0] = t.x; fv[4 * e + 1] = t.y;
    fv[4 * e + 2] = t.z; fv[4 * e + 3] = t.w;
  }
  u16x8 lo, hi;
#pragma unroll
  for (int e = 0; e < 8; ++e) {
    lo[e] = __builtin_bit_cast(unsigned short, (__bf16)fv[e]);
    hi[e] = __builtin_bit_cast(unsigned short, (__bf16)fv[e + 8]);
  }
  *(u16x8*)dst = lo;
  *(u16x8*)(dst + 8) = hi;
}

#define LDS_STRIDE 40
__global__ __launch_bounds__(256, 2)
void hmu_main_f(const float* __restrict__ x, const float* __restrict__ mu,
                const float* __restrict__ lam, const float* __restrict__ v,
                const float* __restrict__ om, const float* __restrict__ ws,
                float* __restrict__ out) {
  __shared__ __align__(16) unsigned short As[BT * LDS_STRIDE];
  __shared__ __align__(16) unsigned short Bs[NT * 9 * LDS_STRIDE];
  const float* ws_x2 = ws;
  const float* ws_mu2 = ws + 1024;
  const float* ws_muv = ws + 9216;
  const int tid = threadIdx.x, lane = tid & 63, w = tid >> 6;
  const int m = lane & 15, kg = lane >> 4;
  const int n0 = blockIdx.x * NT, b0 = blockIdx.y * BT;
  f32x4 acc[2][9];
#pragma unroll
  for (int bs = 0; bs < 2; ++bs)
#pragma unroll
    for (int j = 0; j < 9; ++j) acc[bs][j] = (f32x4){0.f, 0.f, 0.f, 0.f};
  const int arow = tid >> 1, ahalf = tid & 1;
  for (int kt = 0; kt < 8; ++kt) {
    const int k0 = kt * 32;
    cvt16_store(x + (size_t)(b0 + arow) * D_SZ + k0 + ahalf * 16,
                &As[arow * LDS_STRIDE + ahalf * 16]);
#pragma unroll
    for (int it = 0; it < 2; ++it) {
      int idx = tid + 256 * it;
      if (idx < 288) {
        int row = idx >> 1, half = idx & 1;
        int nl = row / 9, j = row - nl * 9;
        const float* src = (j == 0)
            ? mu + (size_t)(n0 + nl) * D_SZ + k0 + half * 16
            : v + (size_t)((n0 + nl) * K_SZ + (j - 1)) * D_SZ + k0 + half * 16;
        cvt16_store(src, &Bs[row * LDS_STRIDE + half * 16]);
      }
    }
    __syncthreads();
    bf16x8 af[2];
#pragma unroll
    for (int bs = 0; bs < 2; ++bs)
      af[bs] = *(const bf16x8*)&As[((2 * w + bs) * 16 + m) * LDS_STRIDE + kg * 8];
#pragma unroll
    for (int j = 0; j < 9; ++j) {
      bf16x8 bfr = *(const bf16x8*)&Bs[(m * 9 + j) * LDS_STRIDE + kg * 8];
      acc[0][j] = __builtin_amdgcn_mfma_f32_16x16x32_bf16(af[0], bfr, acc[0][j], 0, 0, 0);
      acc[1][j] = __builtin_amdgcn_mfma_f32_16x16x32_bf16(af[1], bfr, acc[1][j], 0, 0, 0);
    }
    __syncthreads();
  }
  const int n = n0 + m;
  const float lam_n = lam[n];
  const float mu2_n = ws_mu2[n];
  float omr[8], muvr[8];
#pragma unroll
  for (int k = 0; k < 8; ++k) {
    omr[k] = om[n * 8 + k];
    muvr[k] = ws_muv[n * 8 + k];
  }
#pragma unroll
  for (int bs = 0; bs < 2; ++bs)
#pragma unroll
    for (int r = 0; r < 4; ++r) {
      int b = b0 + (2 * w + bs) * 16 + kg * 4 + r;
      float c0 = acc[bs][0][r];
      float q = lam_n * (ws_x2[b] - 2.f * c0 + mu2_n);
#pragma unroll
      for (int k = 0; k < 8; ++k) {
        float p = acc[bs][k + 1][r] - muvr[k];
        q = fmaf(omr[k] * p, p, q);
      }
      out[(size_t)b * N_SZ + n] = __expf(q * (-1.0f / 256.0f));
    }
}

__global__ void p2_mu_f(const float* __restrict__ mu, const float* __restrict__ v,
                        float* __restrict__ mu2, float* __restrict__ muv) {
  __shared__ __align__(16) float mulds[D_SZ];
  const int n = blockIdx.x;
  const int w = threadIdx.x >> 6, lane = threadIdx.x & 63;
  if (w == 0) {
    float4 m4 = *(const float4*)(mu + (size_t)n * D_SZ + 4 * lane);
    *(float4*)(mulds + 4 * lane) = m4;
    float s = m4.x * m4.x + m4.y * m4.y + m4.z * m4.z + m4.w * m4.w;
    s = wave_reduce(s);
    if (lane == 0) mu2[n] = s;
  }
  __syncthreads();
  float4 m4 = *(const float4*)(mulds + 4 * lane);
#pragma unroll
  for (int kk = 0; kk < 2; ++kk) {
    const int k = w * 2 + kk;
    float4 v4 = *(const float4*)(v + ((size_t)n * K_SZ + k) * D_SZ + 4 * lane);
    float s = m4.x * v4.x + m4.y * v4.y + m4.z * v4.z + m4.w * v4.w;
    s = wave_reduce(s);
    if (lane == 0) muv[n * K_SZ + k] = s;
  }
}

__global__ void p1_x2_f(const float* __restrict__ x, float* __restrict__ x2) {
  const int w = threadIdx.x >> 6, lane = threadIdx.x & 63;
  const int b = blockIdx.x * 4 + w;
  float4 t = *(const float4*)(x + (size_t)b * D_SZ + 4 * lane);
  float s = t.x * t.x + t.y * t.y + t.z * t.z + t.w * t.w;
  s = wave_reduce(s);
  if (lane == 0) x2[b] = s;
}

extern "C" void kernel_launch(void* const* d_in, const int* in_sizes, int n_in,
                              void* d_out, int out_size, void* d_ws, size_t ws_size,
                              hipStream_t stream) {
  const float* x   = (const float*)d_in[0];
  const float* mu  = (const float*)d_in[1];
  const float* lam = (const float*)d_in[2];
  const float* v   = (const float*)d_in[3];
  const float* om  = (const float*)d_in[4];
  float* out = (float*)d_out;
  char* wsb = (char*)d_ws;
  float* wsf = (float*)d_ws;
  float* x2  = (float*)(wsb + WS_X2);
  float* mu2 = (float*)(wsb + WS_MU2);
  float* muv = (float*)(wsb + WS_MUV);

  dim3 grid(N_SZ / NT, B_SZ / BT);
  if (ws_size >= WS_NEED) {
    unsigned short* px = (unsigned short*)(wsb + WS_PX);
    unsigned short* pw = (unsigned short*)(wsb + WS_PW);
    prep_x<<<B_SZ / 4, 256, 0, stream>>>(x, x2, px);
    prep_w<<<N_SZ, 256, 0, stream>>>(mu, v, mu2, muv, pw);
    hmu_main_p<<<grid, 256, 0, stream>>>(px, pw, lam, om, wsf, out);
  } else {
    p1_x2_f<<<B_SZ / 4, 256, 0, stream>>>(x, x2);
    p2_mu_f<<<N_SZ, 256, 0, stream>>>(mu, v, mu2, muv);
    hmu_main_f<<<grid, 256, 0, stream>>>(x, mu, lam, v, om, wsf, out);
  }
}